// Round 2
// baseline (682.425 us; speedup 1.0000x reference)
//
#include <hip/hip_runtime.h>
#include <hip/hip_bf16.h>

// SpiralFC: out[b,o,y,x] = sum_c W[o,c] * x[b, y+dy[c], x+dx[c], c] + bias[o]
// Integer shifts (round() in reference) -> pure shift with zero padding.
//
// Two-phase plan:
//   K1 shift_t_kernel : Xs[m][c] = bf16(x[b, y+dy[c], x+dx[c], c])  (ws)
//                       + Wb[o][c] = bf16(W[o][c])                  (ws)
//   K2 gemm_kernel    : out^T[o][m] = Wb[o][:] . Xs[m][:] + bias[o]
//
// R3: thread-per-channel shift (kills the scalar-gather TA bottleneck).
//   Old scheme gathered along channels: ~22.5M scalar global loads
//   (28 non-uniform chunks/px x 8) -> VMEM addr-throughput bound at
//   ~4cyc/instr = 147us (measured 157, hbm 1.3TB/s only 16%).
//   New scheme: thread owns channel c; loads input pixels [i0,i0+64) at c.
//   Wave = 64 consecutive channels -> 256B contiguous per load instr
//   (fully coalesced). Shift is a REGISTER-LOCAL reindex: output range
//   [i0-s_c, i0+64-s_c) is contiguous per thread -> 2B stores (upper half
//   s=0 stays line-coalesced; lower half scatters but is only ~400K instrs).
//   Boundary zeroing via uniform (y,x) trackers + per-lane validity.
//   Virtual edge tiles (+-448 px) cover shifted-out boundary outputs.
//   No LDS. XCD-chunked bijective swizzle keeps boundary-line co-writers
//   on one XCD L2 (3164 % 8 != 0 -> must use bijective form).

#define HD 56
#define WD 56
#define HW 3136
#define CCH 512
#define NBATCH 32
#define MTOT (NBATCH * HW)          // 100352

#define BM 128
#define BN 128
#define BK 64

#define XS_ELEMS ((size_t)MTOT * CCH)
#define XS_BYTES (XS_ELEMS * 2)            // 102,760,448
#define WB_BYTES ((size_t)CCH * CCH * 2)   // 524,288

typedef __attribute__((ext_vector_type(8))) __bf16 bf16x8;
typedef __attribute__((ext_vector_type(4))) float f32x4;
typedef __attribute__((ext_vector_type(8))) unsigned short ushort8_t;

#define AS1 __attribute__((address_space(1)))
#define AS3 __attribute__((address_space(3)))

__device__ __forceinline__ unsigned short f2bf(float f) {
    __hip_bfloat16 h = __float2bfloat16(f);
    return __builtin_bit_cast(unsigned short, h);
}

__device__ __forceinline__ void load16_lds(const unsigned short* g, unsigned short* l) {
    __builtin_amdgcn_global_load_lds((const AS1 unsigned int*)g,
                                     (AS3 unsigned int*)l, 16, 0, 0);
}

// ---------------------------------------------------------------- K1: shift
#define TILE 64
#define SPAD 448                              // max |s| = 7*56+7 = 399 -> 7 tiles
#define NTILES ((MTOT + 2 * SPAD) / TILE)     // 1582
#define SHIFT_BLOCKS (NTILES * 2)             // 3164 (2 channel-halves)
#define WGT_BLOCKS (CCH * CCH / 8 / 256)      // 128

__global__ __launch_bounds__(256) void shift_t_kernel(
    const float* __restrict__ x,     // [B][H][W][C]
    const float* __restrict__ wgt,   // [O][C]
    const float* __restrict__ offs,  // [C][2]
    unsigned short* __restrict__ Xs, // [M][C] bf16
    unsigned short* __restrict__ Wb) // [O][C] bf16
{
    const int tid = threadIdx.x;
    const int bid0 = (int)blockIdx.x;

    if (bid0 >= SHIFT_BLOCKS) {
        // weight convert: 8 floats / thread
        const int e = (bid0 - SHIFT_BLOCKS) * 256 + tid;
        const float4* src = (const float4*)wgt + (size_t)e * 2;
        float4 a = src[0], b = src[1];
        ushort8_t o;
        o[0] = f2bf(a.x); o[1] = f2bf(a.y); o[2] = f2bf(a.z); o[3] = f2bf(a.w);
        o[4] = f2bf(b.x); o[5] = f2bf(b.y); o[6] = f2bf(b.z); o[7] = f2bf(b.w);
        *(ushort8_t*)(Wb + (size_t)e * 8) = o;
        return;
    }

    // bijective XCD-chunked swizzle over SHIFT_BLOCKS (3164 = 8*395 + 4)
    const int nq = SHIFT_BLOCKS / 8, nr = SHIFT_BLOCKS % 8;
    const int xcd = bid0 & 7;
    const int bid = (xcd < nr ? xcd * (nq + 1) : nr * (nq + 1) + (xcd - nr) * nq)
                    + (bid0 >> 3);

    const int tile = bid >> 1;
    const int half = bid & 1;
    const int c = half * 256 + tid;          // this thread's channel
    const int i0 = tile * TILE - SPAD;       // input pixel window start

    const int dy = (int)offs[2 * c];
    const int dx = (int)offs[2 * c + 1];
    const int s  = dy * WD + dx;             // linear shift (per-lane)

    // uniform (y,x) coords of input pixel i0 (i0 may be negative: bias by HW)
    const int mm = i0 + HW;
    const int pp = mm % HW;
    int yi = pp / WD;
    int xi = pp - yi * WD;

#pragma unroll
    for (int pb = 0; pb < 4; pb++) {
        float v[16];
#pragma unroll
        for (int t = 0; t < 16; t++) {
            const int p = pb * 16 + t;
            const unsigned ui = (unsigned)(i0 + p);
            v[t] = (ui < (unsigned)MTOT) ? x[(size_t)ui * CCH + c] : 0.0f;
        }
#pragma unroll
        for (int t = 0; t < 16; t++) {
            const int p = pb * 16 + t;
            // validity: output (y-dy, x-dx) must be a real in-image source
            const bool valid = ((unsigned)(xi - dx) < (unsigned)WD) &
                               ((unsigned)(yi - dy) < (unsigned)HD);
            const unsigned short uv = valid ? f2bf(v[t]) : (unsigned short)0;
            const unsigned um = (unsigned)(i0 + p - s);
            if (um < (unsigned)MTOT)
                Xs[(size_t)um * CCH + c] = uv;
            // uniform coordinate trackers (scalar)
            xi++;
            if (xi == WD) { xi = 0; yi++; if (yi == HD) yi = 0; }
        }
    }
}

// ----------------------------------------------------------------- K2: GEMM
__global__ __launch_bounds__(256) void gemm_kernel(
    const unsigned short* __restrict__ Xs,   // [M][512] bf16
    const unsigned short* __restrict__ Wb,   // [512][512] bf16
    const float* __restrict__ bias,
    float* __restrict__ out)                 // [B][O][H][W]
{
    __shared__ unsigned short sW[BM * BK];   // 16KB, no pad (global_load_lds)
    __shared__ unsigned short sX[BN * BK];   // 16KB
    __shared__ float sBias[BM];

    const int tid = threadIdx.x;
    // XCD-chunked swizzle (3136 % 8 == 0): each XCD gets 392 consecutive
    // logical blocks = 98 pixel-tiles x 4 o-tiles -> the 4 o-siblings that
    // share one 131KB Xs tile live on the same XCD L2.
    const int bid0 = (int)blockIdx.x;
    const int bid  = (bid0 & 7) * (3136 / 8) + (bid0 >> 3);
    const int ot = bid & 3;
    const int pt = bid >> 2;
    const int O0 = ot * BM;
    const int P0 = pt * BN;

    if (tid < BM) sBias[tid] = bias[O0 + tid];

    const int w   = tid >> 6;
    const int l   = tid & 63;
    const int q   = l >> 4;
    const int c16 = l & 15;
    const int wo  = w & 1;
    const int wm  = w >> 1;

    // XOR swizzle: lds chunk (row, slot) holds global k-chunk slot^(row&7)
    const int lc    = (l & 7) ^ ((l >> 3) & 7);   // staging gather chunk
    const int k7    = c16 & 7;
    const int slot0 = q ^ k7;                     // frag slot, s=0 (chunk q)
    const int slot1 = (4 + q) ^ k7;               // frag slot, s=1 (chunk 4+q)

    f32x4 acc[4][4];
#pragma unroll
    for (int i = 0; i < 4; i++)
#pragma unroll
        for (int j = 0; j < 4; j++) acc[i][j] = (f32x4)0.0f;

    for (int kk = 0; kk < CCH; kk += BK) {
        // stage both tiles: 4+4 wave-issues of 16B/lane direct-to-LDS
#pragma unroll
        for (int i = 0; i < 4; i++) {
            const int ib = w * 4 + i;            // 1KB LDS chunk index
            const int row = ib * 8 + (l >> 3);
            const unsigned short* gW = Wb + (size_t)(O0 + row) * CCH + kk + lc * 8;
            const unsigned short* gX = Xs + (size_t)(P0 + row) * CCH + kk + lc * 8;
            load16_lds(gW, &sW[ib * 512]);
            load16_lds(gX, &sX[ib * 512]);
        }
        __syncthreads();

#pragma unroll
        for (int s = 0; s < 2; s++) {
            const int slot = s ? slot1 : slot0;
            bf16x8 af[4], bf[4];
#pragma unroll
            for (int i = 0; i < 4; i++) {
                const int row = wo * 64 + i * 16 + c16;
                af[i] = *(const bf16x8*)&sW[row * BK + slot * 8];
            }
#pragma unroll
            for (int j = 0; j < 4; j++) {
                const int row = wm * 64 + j * 16 + c16;
                bf[j] = *(const bf16x8*)&sX[row * BK + slot * 8];
            }
#pragma unroll
            for (int i = 0; i < 4; i++)
#pragma unroll
                for (int j = 0; j < 4; j++)
                    acc[i][j] = __builtin_amdgcn_mfma_f32_16x16x32_bf16(
                        af[i], bf[j], acc[i][j], 0, 0, 0);
        }
        __syncthreads();
    }

    // epilogue: D[row=q*4+r][col=c16]; lanes 0..15 sweep consecutive pixels
#pragma unroll
    for (int j = 0; j < 4; j++) {
        const int g = P0 + wm * 64 + j * 16 + c16;
        const int b = g / HW;
        const int p = g - b * HW;
        float* obase = out + (size_t)b * CCH * HW + p;
#pragma unroll
        for (int i = 0; i < 4; i++) {
#pragma unroll
            for (int r = 0; r < 4; r++) {
                const int o_l = wo * 64 + i * 16 + q * 4 + r;
                obase[(size_t)(O0 + o_l) * HW] = acc[i][j][r] + sBias[o_l];
            }
        }
    }
}

// ------------------------------------------------------- fallback (fused R1)
#define LDK 72
__global__ __launch_bounds__(256) void spiralfc_fused(
    const float* __restrict__ x, const float* __restrict__ wgt,
    const float* __restrict__ bias, const float* __restrict__ offs,
    float* __restrict__ out)
{
    __shared__ unsigned short sW[BM * LDK];
    __shared__ unsigned short sX[BN * LDK];
    __shared__ int sDy[CCH];
    __shared__ int sDx[CCH];
    __shared__ float sBias[BM];

    const int tid = threadIdx.x;
    const int bid = blockIdx.x;
    const int O0 = (bid & 3) * BM;
    const int P0 = (bid >> 2) * BN;

    for (int k = tid; k < CCH; k += 256) {
        sDy[k] = (int)offs[2 * k];
        sDx[k] = (int)offs[2 * k + 1];
    }
    if (tid < BM) sBias[tid] = bias[O0 + tid];

    const int w = tid >> 6, l = tid & 63, q = l >> 4, c16 = l & 15;
    const int wo = w & 1, wm = w >> 1;

    f32x4 acc[4][4];
#pragma unroll
    for (int i = 0; i < 4; i++)
#pragma unroll
        for (int j = 0; j < 4; j++) acc[i][j] = (f32x4)0.0f;

    const int kcW = tid & 15, orW = tid >> 4;
    __syncthreads();

    for (int kk = 0; kk < CCH; kk += BK) {
#pragma unroll
        for (int ps = 0; ps < 8; ps++) {
            const int o = ps * 16 + orW;
            const float4 wv = *(const float4*)(wgt + (size_t)(O0 + o) * CCH + kk + kcW * 4);
            ushort4 uv;
            uv.x = f2bf(wv.x); uv.y = f2bf(wv.y); uv.z = f2bf(wv.z); uv.w = f2bf(wv.w);
            *(ushort4*)&sW[o * LDK + kcW * 4] = uv;
        }
#pragma unroll 4
        for (int ps = 0; ps < 32; ps++) {
            const int m = ps * 4 + w;
            const int g = P0 + m;
            const int b = g / HW;
            const int p = g - b * HW;
            const int y = p / WD;
            const int xx = p - y * WD;
            const int k = kk + l;
            const int yy = y + sDy[k];
            const int xs = xx + sDx[k];
            float v = 0.0f;
            if ((unsigned)yy < (unsigned)HD && (unsigned)xs < (unsigned)WD)
                v = x[((size_t)b * HW + yy * WD + xs) * CCH + k];
            sX[m * LDK + l] = f2bf(v);
        }
        __syncthreads();
#pragma unroll
        for (int s = 0; s < 2; s++) {
            bf16x8 af[4], bf[4];
#pragma unroll
            for (int i = 0; i < 4; i++)
                af[i] = *(const bf16x8*)&sW[(wo * 64 + i * 16 + c16) * LDK + s * 32 + q * 8];
#pragma unroll
            for (int j = 0; j < 4; j++)
                bf[j] = *(const bf16x8*)&sX[(wm * 64 + j * 16 + c16) * LDK + s * 32 + q * 8];
#pragma unroll
            for (int i = 0; i < 4; i++)
#pragma unroll
                for (int j = 0; j < 4; j++)
                    acc[i][j] = __builtin_amdgcn_mfma_f32_16x16x32_bf16(
                        af[i], bf[j], acc[i][j], 0, 0, 0);
        }
        __syncthreads();
    }
#pragma unroll
    for (int j = 0; j < 4; j++) {
        const int g = P0 + wm * 64 + j * 16 + c16;
        const int b = g / HW;
        const int p = g - b * HW;
        float* obase = out + (size_t)b * CCH * HW + p;
#pragma unroll
        for (int i = 0; i < 4; i++)
#pragma unroll
            for (int r = 0; r < 4; r++) {
                const int o_l = wo * 64 + i * 16 + q * 4 + r;
                obase[(size_t)(O0 + o_l) * HW] = acc[i][j][r] + sBias[o_l];
            }
    }
}

extern "C" void kernel_launch(void* const* d_in, const int* in_sizes, int n_in,
                              void* d_out, int out_size, void* d_ws, size_t ws_size,
                              hipStream_t stream) {
    const float* x    = (const float*)d_in[0];
    const float* wgt  = (const float*)d_in[1];
    const float* bias = (const float*)d_in[2];
    const float* offs = (const float*)d_in[3];
    float* out = (float*)d_out;

    if (ws_size >= XS_BYTES + WB_BYTES) {
        unsigned short* Xs = (unsigned short*)d_ws;
        unsigned short* Wb = (unsigned short*)((char*)d_ws + XS_BYTES);
        shift_t_kernel<<<dim3(SHIFT_BLOCKS + WGT_BLOCKS), dim3(256), 0, stream>>>(
            x, wgt, offs, Xs, Wb);
        gemm_kernel<<<dim3(3136), dim3(256), 0, stream>>>(Xs, Wb, bias, out);
    } else {
        spiralfc_fused<<<dim3(3136), dim3(256), 0, stream>>>(x, wgt, bias, offs, out);
    }
}

// Round 3
// 497.881 us; speedup vs baseline: 1.3707x; 1.3707x over previous
//
#include <hip/hip_runtime.h>
#include <hip/hip_bf16.h>

// SpiralFC: out[b,o,y,x] = sum_c W[o,c] * x[b, y+dy[c], x+dx[c], c] + bias[o]
// Integer shifts (round() in reference) -> pure shift with zero padding.
//
// Two-phase plan:
//   K1 shift_row_kernel : Xs[m][c] = bf16(x[b, y+dy[c], x+dx[c], c])  (ws)
//                         + Wb[o][c] = bf16(W[o][c])                  (ws)
//   K2 gemm_kernel      : out^T[o][m] = Wb[o][:] . Xs[m][:] + bias[o]
//
// R4 shift design (post-mortem of R3's 3x write-amplification):
//   A per-lane shifted index on EITHER side of a global access scatters
//   2B/lane over ~60 lines -> sector write amplification (measured 305MB
//   vs 101MB ideal) + TA line-split serialization. Fix: absorb the shift
//   in LDS, where per-lane addressing is native.
//   Structural facts: num_dim=256 -> channels 256..511 have ZERO shift
//   (pure copy); channels 0..255 have |dy|,|dx| <= 7, slowly varying
//   (runs of equal dy across consecutive channels -> staging loads
//   coalesce into a few segments per wave).
//   Block = one (image b, output row y):
//     P1: sIn[x][c] = bf16(x[b, y+dy_c, x, c])   (c<256; 0 if row OOB)
//         lane=channel, 56 x-iters; dy-runs keep loads segment-coalesced.
//     P2: Xs[b,y,x][c] = (0<=x+dx_c<56) ? sIn[x+dx_c][c] : 0
//         dx shift lives in the LDS READ address (bank = f(c) only, 2-way
//         free); global stores 128B-contiguous per wave-instr.
//     P3: upper half c>=256: float4 -> bf16x4 straight copy (1KB/512B per
//         wave-instr).
//   WRITE_SIZE returns to ~101MB by construction; no global scatter left.

#define HD 56
#define WD 56
#define HW 3136
#define CCH 512
#define NBATCH 32
#define MTOT (NBATCH * HW)          // 100352

#define BM 128
#define BN 128
#define BK 64

#define XS_ELEMS ((size_t)MTOT * CCH)
#define XS_BYTES (XS_ELEMS * 2)            // 102,760,448
#define WB_BYTES ((size_t)CCH * CCH * 2)   // 524,288

typedef __attribute__((ext_vector_type(8))) __bf16 bf16x8;
typedef __attribute__((ext_vector_type(4))) float f32x4;
typedef __attribute__((ext_vector_type(8))) unsigned short ushort8_t;

#define AS1 __attribute__((address_space(1)))
#define AS3 __attribute__((address_space(3)))

__device__ __forceinline__ unsigned short f2bf(float f) {
    __hip_bfloat16 h = __float2bfloat16(f);
    return __builtin_bit_cast(unsigned short, h);
}

__device__ __forceinline__ void load16_lds(const unsigned short* g, unsigned short* l) {
    __builtin_amdgcn_global_load_lds((const AS1 unsigned int*)g,
                                     (AS3 unsigned int*)l, 16, 0, 0);
}

// ---------------------------------------------------------------- K1: shift
#define SROW_BLOCKS (NBATCH * HD)             // 1792 (% 8 == 0)
#define WGT_BLOCKS (CCH * CCH / 8 / 256)      // 128

__global__ __launch_bounds__(256) void shift_row_kernel(
    const float* __restrict__ x,     // [B][H][W][C]
    const float* __restrict__ wgt,   // [O][C]
    const float* __restrict__ offs,  // [C][2]
    unsigned short* __restrict__ Xs, // [M][C] bf16
    unsigned short* __restrict__ Wb) // [O][C] bf16
{
    const int tid = threadIdx.x;
    const int bid0 = (int)blockIdx.x;

    if (bid0 >= SROW_BLOCKS) {
        // weight convert: 8 floats / thread
        const int e = (bid0 - SROW_BLOCKS) * 256 + tid;
        const float4* src = (const float4*)wgt + (size_t)e * 2;
        float4 a = src[0], b = src[1];
        ushort8_t o;
        o[0] = f2bf(a.x); o[1] = f2bf(a.y); o[2] = f2bf(a.z); o[3] = f2bf(a.w);
        o[4] = f2bf(b.x); o[5] = f2bf(b.y); o[6] = f2bf(b.z); o[7] = f2bf(b.w);
        *(ushort8_t*)(Wb + (size_t)e * 8) = o;
        return;
    }

    // XCD-chunked swizzle (1792 % 8 == 0): XCD k owns a contiguous run of
    // (b,y) rows -> adjacent rows sharing boundary lines hit the same L2.
    const int lb = (bid0 & 7) * (SROW_BLOCKS / 8) + (bid0 >> 3);
    const int b = lb / HD;
    const int y = lb - b * HD;

    __shared__ unsigned short sIn[WD * 256];   // 28 KB (lower channels only)

    const int c  = tid;                        // 0..255 = lower channel
    const int dy = (int)offs[2 * c];
    const int dx = (int)offs[2 * c + 1];
    const int yy = y + dy;
    const bool rowok = (unsigned)yy < (unsigned)HD;
    const float* rowp = x + ((size_t)b * HD + (rowok ? yy : 0)) * WD * CCH + c;

    // P1: stage shifted row (dy applied) for lower channels
#pragma unroll 4
    for (int xx = 0; xx < WD; xx++) {
        float v = 0.0f;
        if (rowok) v = rowp[(size_t)xx * CCH];
        sIn[xx * 256 + c] = f2bf(v);
    }
    __syncthreads();

    // P2: apply dx via LDS read address; stores contiguous
    unsigned short* orow = Xs + ((size_t)b * HW + (size_t)y * WD) * CCH;
#pragma unroll 4
    for (int xx = 0; xx < WD; xx++) {
        const int xs = xx + dx;
        unsigned short v = 0;
        if ((unsigned)xs < (unsigned)WD) v = sIn[xs * 256 + c];
        orow[(size_t)xx * CCH + c] = v;
    }

    // P3: upper half (c >= 256): zero shift -> straight copy/convert
    const float* ibase = x + ((size_t)b * HW + (size_t)y * WD) * CCH;
#pragma unroll
    for (int it = 0; it < 14; it++) {
        const int e = it * 256 + tid;       // 0..3583
        const int xx = e >> 6;              // 64 float4-chunks per pixel-row
        const int cq = e & 63;
        const int cc = 256 + cq * 4;
        float4 v = *(const float4*)(ibase + (size_t)xx * CCH + cc);
        ushort4 u;
        u.x = f2bf(v.x); u.y = f2bf(v.y); u.z = f2bf(v.z); u.w = f2bf(v.w);
        *(ushort4*)(orow + (size_t)xx * CCH + cc) = u;
    }
}

// ----------------------------------------------------------------- K2: GEMM
__global__ __launch_bounds__(256) void gemm_kernel(
    const unsigned short* __restrict__ Xs,   // [M][512] bf16
    const unsigned short* __restrict__ Wb,   // [512][512] bf16
    const float* __restrict__ bias,
    float* __restrict__ out)                 // [B][O][H][W]
{
    __shared__ unsigned short sW[BM * BK];   // 16KB, no pad (global_load_lds)
    __shared__ unsigned short sX[BN * BK];   // 16KB
    __shared__ float sBias[BM];

    const int tid = threadIdx.x;
    // XCD-chunked swizzle (3136 % 8 == 0): each XCD gets 392 consecutive
    // logical blocks = 98 pixel-tiles x 4 o-tiles -> the 4 o-siblings that
    // share one 131KB Xs tile live on the same XCD L2.
    const int bid0 = (int)blockIdx.x;
    const int bid  = (bid0 & 7) * (3136 / 8) + (bid0 >> 3);
    const int ot = bid & 3;
    const int pt = bid >> 2;
    const int O0 = ot * BM;
    const int P0 = pt * BN;

    if (tid < BM) sBias[tid] = bias[O0 + tid];

    const int w   = tid >> 6;
    const int l   = tid & 63;
    const int q   = l >> 4;
    const int c16 = l & 15;
    const int wo  = w & 1;
    const int wm  = w >> 1;

    // XOR swizzle: lds chunk (row, slot) holds global k-chunk slot^(row&7)
    const int lc    = (l & 7) ^ ((l >> 3) & 7);   // staging gather chunk
    const int k7    = c16 & 7;
    const int slot0 = q ^ k7;                     // frag slot, s=0 (chunk q)
    const int slot1 = (4 + q) ^ k7;               // frag slot, s=1 (chunk 4+q)

    f32x4 acc[4][4];
#pragma unroll
    for (int i = 0; i < 4; i++)
#pragma unroll
        for (int j = 0; j < 4; j++) acc[i][j] = (f32x4)0.0f;

    for (int kk = 0; kk < CCH; kk += BK) {
        // stage both tiles: 4+4 wave-issues of 16B/lane direct-to-LDS
#pragma unroll
        for (int i = 0; i < 4; i++) {
            const int ib = w * 4 + i;            // 1KB LDS chunk index
            const int row = ib * 8 + (l >> 3);
            const unsigned short* gW = Wb + (size_t)(O0 + row) * CCH + kk + lc * 8;
            const unsigned short* gX = Xs + (size_t)(P0 + row) * CCH + kk + lc * 8;
            load16_lds(gW, &sW[ib * 512]);
            load16_lds(gX, &sX[ib * 512]);
        }
        __syncthreads();

#pragma unroll
        for (int s = 0; s < 2; s++) {
            const int slot = s ? slot1 : slot0;
            bf16x8 af[4], bf[4];
#pragma unroll
            for (int i = 0; i < 4; i++) {
                const int row = wo * 64 + i * 16 + c16;
                af[i] = *(const bf16x8*)&sW[row * BK + slot * 8];
            }
#pragma unroll
            for (int j = 0; j < 4; j++) {
                const int row = wm * 64 + j * 16 + c16;
                bf[j] = *(const bf16x8*)&sX[row * BK + slot * 8];
            }
#pragma unroll
            for (int i = 0; i < 4; i++)
#pragma unroll
                for (int j = 0; j < 4; j++)
                    acc[i][j] = __builtin_amdgcn_mfma_f32_16x16x32_bf16(
                        af[i], bf[j], acc[i][j], 0, 0, 0);
        }
        __syncthreads();
    }

    // epilogue: D[row=q*4+r][col=c16]; lanes 0..15 sweep consecutive pixels
#pragma unroll
    for (int j = 0; j < 4; j++) {
        const int g = P0 + wm * 64 + j * 16 + c16;
        const int b = g / HW;
        const int p = g - b * HW;
        float* obase = out + (size_t)b * CCH * HW + p;
#pragma unroll
        for (int i = 0; i < 4; i++) {
#pragma unroll
            for (int r = 0; r < 4; r++) {
                const int o_l = wo * 64 + i * 16 + q * 4 + r;
                obase[(size_t)(O0 + o_l) * HW] = acc[i][j][r] + sBias[o_l];
            }
        }
    }
}

// ------------------------------------------------------- fallback (fused R1)
#define LDK 72
__global__ __launch_bounds__(256) void spiralfc_fused(
    const float* __restrict__ x, const float* __restrict__ wgt,
    const float* __restrict__ bias, const float* __restrict__ offs,
    float* __restrict__ out)
{
    __shared__ unsigned short sW[BM * LDK];
    __shared__ unsigned short sX[BN * LDK];
    __shared__ int sDy[CCH];
    __shared__ int sDx[CCH];
    __shared__ float sBias[BM];

    const int tid = threadIdx.x;
    const int bid = blockIdx.x;
    const int O0 = (bid & 3) * BM;
    const int P0 = (bid >> 2) * BN;

    for (int k = tid; k < CCH; k += 256) {
        sDy[k] = (int)offs[2 * k];
        sDx[k] = (int)offs[2 * k + 1];
    }
    if (tid < BM) sBias[tid] = bias[O0 + tid];

    const int w = tid >> 6, l = tid & 63, q = l >> 4, c16 = l & 15;
    const int wo = w & 1, wm = w >> 1;

    f32x4 acc[4][4];
#pragma unroll
    for (int i = 0; i < 4; i++)
#pragma unroll
        for (int j = 0; j < 4; j++) acc[i][j] = (f32x4)0.0f;

    const int kcW = tid & 15, orW = tid >> 4;
    __syncthreads();

    for (int kk = 0; kk < CCH; kk += BK) {
#pragma unroll
        for (int ps = 0; ps < 8; ps++) {
            const int o = ps * 16 + orW;
            const float4 wv = *(const float4*)(wgt + (size_t)(O0 + o) * CCH + kk + kcW * 4);
            ushort4 uv;
            uv.x = f2bf(wv.x); uv.y = f2bf(wv.y); uv.z = f2bf(wv.z); uv.w = f2bf(wv.w);
            *(ushort4*)&sW[o * LDK + kcW * 4] = uv;
        }
#pragma unroll 4
        for (int ps = 0; ps < 32; ps++) {
            const int m = ps * 4 + w;
            const int g = P0 + m;
            const int b = g / HW;
            const int p = g - b * HW;
            const int y = p / WD;
            const int xx = p - y * WD;
            const int k = kk + l;
            const int yy = y + sDy[k];
            const int xs = xx + sDx[k];
            float v = 0.0f;
            if ((unsigned)yy < (unsigned)HD && (unsigned)xs < (unsigned)WD)
                v = x[((size_t)b * HW + yy * WD + xs) * CCH + k];
            sX[m * LDK + l] = f2bf(v);
        }
        __syncthreads();
#pragma unroll
        for (int s = 0; s < 2; s++) {
            bf16x8 af[4], bf[4];
#pragma unroll
            for (int i = 0; i < 4; i++)
                af[i] = *(const bf16x8*)&sW[(wo * 64 + i * 16 + c16) * LDK + s * 32 + q * 8];
#pragma unroll
            for (int j = 0; j < 4; j++)
                bf[j] = *(const bf16x8*)&sX[(wm * 64 + j * 16 + c16) * LDK + s * 32 + q * 8];
#pragma unroll
            for (int i = 0; i < 4; i++)
#pragma unroll
                for (int j = 0; j < 4; j++)
                    acc[i][j] = __builtin_amdgcn_mfma_f32_16x16x32_bf16(
                        af[i], bf[j], acc[i][j], 0, 0, 0);
        }
        __syncthreads();
    }
#pragma unroll
    for (int j = 0; j < 4; j++) {
        const int g = P0 + wm * 64 + j * 16 + c16;
        const int b = g / HW;
        const int p = g - b * HW;
        float* obase = out + (size_t)b * CCH * HW + p;
#pragma unroll
        for (int i = 0; i < 4; i++)
#pragma unroll
            for (int r = 0; r < 4; r++) {
                const int o_l = wo * 64 + i * 16 + q * 4 + r;
                obase[(size_t)(O0 + o_l) * HW] = acc[i][j][r] + sBias[o_l];
            }
    }
}

extern "C" void kernel_launch(void* const* d_in, const int* in_sizes, int n_in,
                              void* d_out, int out_size, void* d_ws, size_t ws_size,
                              hipStream_t stream) {
    const float* x    = (const float*)d_in[0];
    const float* wgt  = (const float*)d_in[1];
    const float* bias = (const float*)d_in[2];
    const float* offs = (const float*)d_in[3];
    float* out = (float*)d_out;

    if (ws_size >= XS_BYTES + WB_BYTES) {
        unsigned short* Xs = (unsigned short*)d_ws;
        unsigned short* Wb = (unsigned short*)((char*)d_ws + XS_BYTES);
        shift_row_kernel<<<dim3(SROW_BLOCKS + WGT_BLOCKS), dim3(256), 0, stream>>>(
            x, wgt, offs, Xs, Wb);
        gemm_kernel<<<dim3(3136), dim3(256), 0, stream>>>(Xs, Wb, bias, out);
    } else {
        spiralfc_fused<<<dim3(3136), dim3(256), 0, stream>>>(x, wgt, bias, offs, out);
    }
}

// Round 4
// 492.502 us; speedup vs baseline: 1.3856x; 1.0109x over previous
//
#include <hip/hip_runtime.h>
#include <hip/hip_bf16.h>

// SpiralFC: out[b,o,y,x] = sum_c W[o,c] * x[b, y+dy[c], x+dx[c], c] + bias[o]
// Integer shifts (round() in reference) -> pure shift with zero padding.
//
// Two-phase plan:
//   K1 shift_row_kernel : Xs[m][c] = bf16(x[b, y+dy[c], x+dx[c], c])  (ws)
//                         + Wb[o][c] = bf16(W[o][c])                  (ws)
//   K2 gemm_kernel      : out^T[o][m] = Wb[o][:] . Xs[m][:] + bias[o]
//
// R4 shift design: absorb shift in LDS (R3 lesson: per-lane shifted global
// index -> sector scatter, 3x write amplification).
// R5 (this round): latency hiding. R4 measured 142us at 1.47TB/s, VALUBusy
// 4%, occupancy 43% -> latency-bound: unroll-4 gave only 4-deep MLP and
// 28KB LDS capped residency at 5 blocks/CU. Fix:
//   - block = (row, channel-half): LDS 14KB, 2x blocks, wave-cap 8 blk/CU
//   - P1 reg-batched loads (14 deep) before LDS writes
//   - P2/P3 fully unrolled
// Traffic identical (~103MB fetch + 101MB write); floor ~34us.

#define HD 56
#define WD 56
#define HW 3136
#define CCH 512
#define NBATCH 32
#define MTOT (NBATCH * HW)          // 100352

#define BM 128
#define BN 128
#define BK 64

#define XS_ELEMS ((size_t)MTOT * CCH)
#define XS_BYTES (XS_ELEMS * 2)            // 102,760,448
#define WB_BYTES ((size_t)CCH * CCH * 2)   // 524,288

typedef __attribute__((ext_vector_type(8))) __bf16 bf16x8;
typedef __attribute__((ext_vector_type(4))) float f32x4;
typedef __attribute__((ext_vector_type(8))) unsigned short ushort8_t;

#define AS1 __attribute__((address_space(1)))
#define AS3 __attribute__((address_space(3)))

__device__ __forceinline__ unsigned short f2bf(float f) {
    __hip_bfloat16 h = __float2bfloat16(f);
    return __builtin_bit_cast(unsigned short, h);
}

__device__ __forceinline__ void load16_lds(const unsigned short* g, unsigned short* l) {
    __builtin_amdgcn_global_load_lds((const AS1 unsigned int*)g,
                                     (AS3 unsigned int*)l, 16, 0, 0);
}

// ---------------------------------------------------------------- K1: shift
#define SROW_BLOCKS (NBATCH * HD * 2)         // 3584 (% 8 == 0): (row, chan-half)
#define WGT_BLOCKS (CCH * CCH / 8 / 256)      // 128

__global__ __launch_bounds__(256) void shift_row_kernel(
    const float* __restrict__ x,     // [B][H][W][C]
    const float* __restrict__ wgt,   // [O][C]
    const float* __restrict__ offs,  // [C][2]
    unsigned short* __restrict__ Xs, // [M][C] bf16
    unsigned short* __restrict__ Wb) // [O][C] bf16
{
    const int tid = threadIdx.x;
    const int bid0 = (int)blockIdx.x;

    if (bid0 >= SROW_BLOCKS) {
        // weight convert: 8 floats / thread
        const int e = (bid0 - SROW_BLOCKS) * 256 + tid;
        const float4* src = (const float4*)wgt + (size_t)e * 2;
        float4 a = src[0], b = src[1];
        ushort8_t o;
        o[0] = f2bf(a.x); o[1] = f2bf(a.y); o[2] = f2bf(a.z); o[3] = f2bf(a.w);
        o[4] = f2bf(b.x); o[5] = f2bf(b.y); o[6] = f2bf(b.z); o[7] = f2bf(b.w);
        *(ushort8_t*)(Wb + (size_t)e * 8) = o;
        return;
    }

    // XCD-chunked swizzle (3584 % 8 == 0): XCD k owns contiguous (b,y) rows.
    const int lb = (bid0 & 7) * (SROW_BLOCKS / 8) + (bid0 >> 3);
    const int row  = lb >> 1;
    const int half = lb & 1;                   // which 128 of the lower 256 ch
    const int b = row / HD;
    const int y = row - b * HD;

    __shared__ unsigned short sIn[WD * 128];   // 14 KB

    const int ci = tid & 127;                  // channel-in-block
    const int h  = tid >> 7;                   // x-window selector (0/1)
    const int c  = half * 128 + ci;            // channel in [0,256)

    const int dy = (int)offs[2 * c];
    const int dx = (int)offs[2 * c + 1];
    const int yy = y + dy;
    const bool rowok = (unsigned)yy < (unsigned)HD;
    const float* rowp = x + ((size_t)b * HD + (rowok ? yy : 0)) * WD * CCH + c;
    const int x0 = h * 28;

    // P1: stage dy-shifted row, 2 reg-batches of 14 independent loads
#pragma unroll
    for (int bt = 0; bt < 2; bt++) {
        float v[14];
#pragma unroll
        for (int t = 0; t < 14; t++) {
            const int xx = x0 + bt * 14 + t;
            v[t] = rowok ? rowp[(size_t)xx * CCH] : 0.0f;
        }
#pragma unroll
        for (int t = 0; t < 14; t++) {
            const int xx = x0 + bt * 14 + t;
            sIn[xx * 128 + ci] = f2bf(v[t]);
        }
    }
    __syncthreads();

    // P2: apply dx via LDS read address (bank = f(ci) only, 2-way free);
    // global stores 128B-contiguous per wave
    unsigned short* orow = Xs + ((size_t)b * HW + (size_t)y * WD) * CCH;
#pragma unroll
    for (int k = 0; k < 28; k++) {
        const int xx = x0 + k;
        const int xs = xx + dx;
        unsigned short u = 0;
        if ((unsigned)xs < (unsigned)WD) u = sIn[xs * 128 + ci];
        orow[(size_t)xx * CCH + c] = u;
    }

    // P3: upper half (c >= 256, zero shift): this block copies half the row
    const float* ibase = x + ((size_t)b * HW + (size_t)y * WD) * CCH;
#pragma unroll
    for (int it = 0; it < 7; it++) {
        const int e = half * 1792 + it * 256 + tid;  // float4-chunk in row
        const int px = e >> 6;
        const int cc = 256 + (e & 63) * 4;
        float4 v = *(const float4*)(ibase + (size_t)px * CCH + cc);
        ushort4 u;
        u.x = f2bf(v.x); u.y = f2bf(v.y); u.z = f2bf(v.z); u.w = f2bf(v.w);
        *(ushort4*)(orow + (size_t)px * CCH + cc) = u;
    }
}

// ----------------------------------------------------------------- K2: GEMM
__global__ __launch_bounds__(256) void gemm_kernel(
    const unsigned short* __restrict__ Xs,   // [M][512] bf16
    const unsigned short* __restrict__ Wb,   // [512][512] bf16
    const float* __restrict__ bias,
    float* __restrict__ out)                 // [B][O][H][W]
{
    __shared__ unsigned short sW[BM * BK];   // 16KB, no pad (global_load_lds)
    __shared__ unsigned short sX[BN * BK];   // 16KB
    __shared__ float sBias[BM];

    const int tid = threadIdx.x;
    // XCD-chunked swizzle (3136 % 8 == 0): each XCD gets 392 consecutive
    // logical blocks = 98 pixel-tiles x 4 o-tiles -> the 4 o-siblings that
    // share one 131KB Xs tile live on the same XCD L2.
    const int bid0 = (int)blockIdx.x;
    const int bid  = (bid0 & 7) * (3136 / 8) + (bid0 >> 3);
    const int ot = bid & 3;
    const int pt = bid >> 2;
    const int O0 = ot * BM;
    const int P0 = pt * BN;

    if (tid < BM) sBias[tid] = bias[O0 + tid];

    const int w   = tid >> 6;
    const int l   = tid & 63;
    const int q   = l >> 4;
    const int c16 = l & 15;
    const int wo  = w & 1;
    const int wm  = w >> 1;

    // XOR swizzle: lds chunk (row, slot) holds global k-chunk slot^(row&7)
    const int lc    = (l & 7) ^ ((l >> 3) & 7);   // staging gather chunk
    const int k7    = c16 & 7;
    const int slot0 = q ^ k7;                     // frag slot, s=0 (chunk q)
    const int slot1 = (4 + q) ^ k7;               // frag slot, s=1 (chunk 4+q)

    f32x4 acc[4][4];
#pragma unroll
    for (int i = 0; i < 4; i++)
#pragma unroll
        for (int j = 0; j < 4; j++) acc[i][j] = (f32x4)0.0f;

    for (int kk = 0; kk < CCH; kk += BK) {
        // stage both tiles: 4+4 wave-issues of 16B/lane direct-to-LDS
#pragma unroll
        for (int i = 0; i < 4; i++) {
            const int ib = w * 4 + i;            // 1KB LDS chunk index
            const int row = ib * 8 + (l >> 3);
            const unsigned short* gW = Wb + (size_t)(O0 + row) * CCH + kk + lc * 8;
            const unsigned short* gX = Xs + (size_t)(P0 + row) * CCH + kk + lc * 8;
            load16_lds(gW, &sW[ib * 512]);
            load16_lds(gX, &sX[ib * 512]);
        }
        __syncthreads();

#pragma unroll
        for (int s = 0; s < 2; s++) {
            const int slot = s ? slot1 : slot0;
            bf16x8 af[4], bf[4];
#pragma unroll
            for (int i = 0; i < 4; i++) {
                const int row = wo * 64 + i * 16 + c16;
                af[i] = *(const bf16x8*)&sW[row * BK + slot * 8];
            }
#pragma unroll
            for (int j = 0; j < 4; j++) {
                const int row = wm * 64 + j * 16 + c16;
                bf[j] = *(const bf16x8*)&sX[row * BK + slot * 8];
            }
#pragma unroll
            for (int i = 0; i < 4; i++)
#pragma unroll
                for (int j = 0; j < 4; j++)
                    acc[i][j] = __builtin_amdgcn_mfma_f32_16x16x32_bf16(
                        af[i], bf[j], acc[i][j], 0, 0, 0);
        }
        __syncthreads();
    }

    // epilogue: D[row=q*4+r][col=c16]; lanes 0..15 sweep consecutive pixels
#pragma unroll
    for (int j = 0; j < 4; j++) {
        const int g = P0 + wm * 64 + j * 16 + c16;
        const int b = g / HW;
        const int p = g - b * HW;
        float* obase = out + (size_t)b * CCH * HW + p;
#pragma unroll
        for (int i = 0; i < 4; i++) {
#pragma unroll
            for (int r = 0; r < 4; r++) {
                const int o_l = wo * 64 + i * 16 + q * 4 + r;
                obase[(size_t)(O0 + o_l) * HW] = acc[i][j][r] + sBias[o_l];
            }
        }
    }
}

// ------------------------------------------------------- fallback (fused R1)
#define LDK 72
__global__ __launch_bounds__(256) void spiralfc_fused(
    const float* __restrict__ x, const float* __restrict__ wgt,
    const float* __restrict__ bias, const float* __restrict__ offs,
    float* __restrict__ out)
{
    __shared__ unsigned short sW[BM * LDK];
    __shared__ unsigned short sX[BN * LDK];
    __shared__ int sDy[CCH];
    __shared__ int sDx[CCH];
    __shared__ float sBias[BM];

    const int tid = threadIdx.x;
    const int bid = blockIdx.x;
    const int O0 = (bid & 3) * BM;
    const int P0 = (bid >> 2) * BN;

    for (int k = tid; k < CCH; k += 256) {
        sDy[k] = (int)offs[2 * k];
        sDx[k] = (int)offs[2 * k + 1];
    }
    if (tid < BM) sBias[tid] = bias[O0 + tid];

    const int w = tid >> 6, l = tid & 63, q = l >> 4, c16 = l & 15;
    const int wo = w & 1, wm = w >> 1;

    f32x4 acc[4][4];
#pragma unroll
    for (int i = 0; i < 4; i++)
#pragma unroll
        for (int j = 0; j < 4; j++) acc[i][j] = (f32x4)0.0f;

    const int kcW = tid & 15, orW = tid >> 4;
    __syncthreads();

    for (int kk = 0; kk < CCH; kk += BK) {
#pragma unroll
        for (int ps = 0; ps < 8; ps++) {
            const int o = ps * 16 + orW;
            const float4 wv = *(const float4*)(wgt + (size_t)(O0 + o) * CCH + kk + kcW * 4);
            ushort4 uv;
            uv.x = f2bf(wv.x); uv.y = f2bf(wv.y); uv.z = f2bf(wv.z); uv.w = f2bf(wv.w);
            *(ushort4*)&sW[o * LDK + kcW * 4] = uv;
        }
#pragma unroll 4
        for (int ps = 0; ps < 32; ps++) {
            const int m = ps * 4 + w;
            const int g = P0 + m;
            const int b = g / HW;
            const int p = g - b * HW;
            const int y = p / WD;
            const int xx = p - y * WD;
            const int k = kk + l;
            const int yy = y + sDy[k];
            const int xs = xx + sDx[k];
            float v = 0.0f;
            if ((unsigned)yy < (unsigned)HD && (unsigned)xs < (unsigned)WD)
                v = x[((size_t)b * HW + yy * WD + xs) * CCH + k];
            sX[m * LDK + l] = f2bf(v);
        }
        __syncthreads();
#pragma unroll
        for (int s = 0; s < 2; s++) {
            bf16x8 af[4], bf[4];
#pragma unroll
            for (int i = 0; i < 4; i++)
                af[i] = *(const bf16x8*)&sW[(wo * 64 + i * 16 + c16) * LDK + s * 32 + q * 8];
#pragma unroll
            for (int j = 0; j < 4; j++)
                bf[j] = *(const bf16x8*)&sX[(wm * 64 + j * 16 + c16) * LDK + s * 32 + q * 8];
#pragma unroll
            for (int i = 0; i < 4; i++)
#pragma unroll
                for (int j = 0; j < 4; j++)
                    acc[i][j] = __builtin_amdgcn_mfma_f32_16x16x32_bf16(
                        af[i], bf[j], acc[i][j], 0, 0, 0);
        }
        __syncthreads();
    }
#pragma unroll
    for (int j = 0; j < 4; j++) {
        const int g = P0 + wm * 64 + j * 16 + c16;
        const int b = g / HW;
        const int p = g - b * HW;
        float* obase = out + (size_t)b * CCH * HW + p;
#pragma unroll
        for (int i = 0; i < 4; i++)
#pragma unroll
            for (int r = 0; r < 4; r++) {
                const int o_l = wo * 64 + i * 16 + q * 4 + r;
                obase[(size_t)(O0 + o_l) * HW] = acc[i][j][r] + sBias[o_l];
            }
    }
}

extern "C" void kernel_launch(void* const* d_in, const int* in_sizes, int n_in,
                              void* d_out, int out_size, void* d_ws, size_t ws_size,
                              hipStream_t stream) {
    const float* x    = (const float*)d_in[0];
    const float* wgt  = (const float*)d_in[1];
    const float* bias = (const float*)d_in[2];
    const float* offs = (const float*)d_in[3];
    float* out = (float*)d_out;

    if (ws_size >= XS_BYTES + WB_BYTES) {
        unsigned short* Xs = (unsigned short*)d_ws;
        unsigned short* Wb = (unsigned short*)((char*)d_ws + XS_BYTES);
        shift_row_kernel<<<dim3(SROW_BLOCKS + WGT_BLOCKS), dim3(256), 0, stream>>>(
            x, wgt, offs, Xs, Wb);
        gemm_kernel<<<dim3(3136), dim3(256), 0, stream>>>(Xs, Wb, bias, out);
    } else {
        spiralfc_fused<<<dim3(3136), dim3(256), 0, stream>>>(x, wgt, bias, offs, out);
    }
}